// Round 9
// baseline (167.212 us; speedup 1.0000x reference)
//
#include <hip/hip_runtime.h>
#include <hip/hip_bf16.h>
#include <stdint.h>

#define B_ 4
#define L_ 2048
#define H_ 8
#define E_ 64
#define ALPHA 0.1f
#define LOG2E 1.44269504088896f
// Q prescale: 1/sqrt(64) * log2(e) folded into projected Q so P = exp2(S)
#define QSCALE (0.125f * LOG2E)

// Tiles are contiguous 64*128B = 8192B, DMA'd verbatim to LDS.
// K tile image: row r (0..63), 16B chunk c (0..7) stored at chunk c ^ (r&7).
// V tile image: row d (0..63), 8B  chunk c (0..15) stored at chunk c ^ (d&15).
// XOR swizzle is applied identically on the prep write side (global) and the
// flash read side (LDS) -> DMA stays linear, reads are bank-conflict-free.

typedef float f32x4 __attribute__((ext_vector_type(4)));
typedef short bf16x8 __attribute__((ext_vector_type(8)));
typedef short bf16x4 __attribute__((ext_vector_type(4)));
typedef uint32_t u32;
typedef unsigned short u16;
typedef u32 u32x2 __attribute__((ext_vector_type(2)));

__device__ __forceinline__ u16 f2bf(float f) {
    u32 x = __builtin_bit_cast(u32, f);
    u32 r = x + 0x7fffu + ((x >> 16) & 1u);   // round-to-nearest-even
    return (u16)(r >> 16);
}

// pack two positive floats to packed bf16 (round-half-up; P>0, never NaN).
// NOTE (r6 post-mortem): v_cvt_pk_bf16_f32 inline asm here FAILED correctness
// (absmax 0.47). Keep the verified bit-op version.
__device__ __forceinline__ u32 pk2bf(float a, float b) {
    u32 ua = __builtin_bit_cast(u32, a) + 0x8000u;
    u32 ub = __builtin_bit_cast(u32, b) + 0x8000u;
    return (ua >> 16) | (ub & 0xffff0000u);
}

__device__ __forceinline__ f32x4 mfma16x16x16bf16(bf16x4 a, bf16x4 b, f32x4 c) {
#if __has_builtin(__builtin_amdgcn_mfma_f32_16x16x16bf16_1k)
    return __builtin_amdgcn_mfma_f32_16x16x16bf16_1k(a, b, c, 0, 0, 0);
#elif __has_builtin(__builtin_amdgcn_mfma_f32_16x16x16_bf16)
    return __builtin_amdgcn_mfma_f32_16x16x16_bf16(a, b, c, 0, 0, 0);
#else
    f32x4 d;
    asm volatile("v_mfma_f32_16x16x16_bf16 %0, %1, %2, %3"
                 : "=v"(d) : "v"(a), "v"(b), "v"(c));
    return d;
#endif
}

// async DMA: 64 lanes x 16B, dest = wave-uniform LDS base + lane*16
__device__ __forceinline__ void dma16(const u16* g, u16* l) {
    __builtin_amdgcn_global_load_lds(
        (const __attribute__((address_space(1))) void*)g,
        (__attribute__((address_space(3))) void*)l, 16, 0, 0);
}

// ---------------------------------------------------------------------------
// Prep kernel (fused): unchanged from v17/v18 (passing, ~4.5us, L3-fed).
// ---------------------------------------------------------------------------
__global__ __launch_bounds__(256) void prep_kernel(const float* __restrict__ qin,
                                                   const float* __restrict__ kin,
                                                   const float* __restrict__ vin,
                                                   u16* __restrict__ qp,
                                                   u16* __restrict__ kp,
                                                   u16* __restrict__ vt) {
    __shared__ u16 tile[64][66];
    if (blockIdx.x < 4096) {
        const int RG = (B_ * L_ * H_) / 8;
        int wave = threadIdx.x >> 6, lane = threadIdx.x & 63;
        int g = blockIdx.x * 4 + wave;
        const float* src;
        u16* dst;
        int gr;
        float sc;
        bool isq;
        if (g < RG) { src = qin; dst = qp; gr = g; sc = QSCALE; isq = true; }
        else        { src = kin; dst = kp; gr = g - RG; sc = 1.0f; isq = false; }

        int rig = lane >> 3;
        int j = lane & 7;
        int c = j * 4;
        int row = gr * 8 + rig;

        const float* rp = src + (size_t)row * 64;
        float4 v0 = *(const float4*)(rp + c);
        float4 v1 = *(const float4*)(rp + c + 32);
        float f[8] = {v0.x, v0.y, v0.z, v0.w, v1.x, v1.y, v1.z, v1.w};

        float mx = 0.f;
#pragma unroll
        for (int i = 0; i < 8; ++i) mx = fmaxf(mx, fabsf(f[i]));
#pragma unroll
        for (int m = 1; m < 8; m <<= 1) mx = fmaxf(mx, __shfl_xor(mx, m));
        float thr = ALPHA * mx;

        u16 o[8];
#pragma unroll
        for (int i = 0; i < 8; ++i)
            o[i] = (fabsf(f[i]) >= thr) ? f2bf(f[i] * sc) : (u16)0;

        int b = row >> 14;
        int l = (row >> 3) & (L_ - 1);
        int h = row & 7;
        // element offsets for the two 8B writes (logical chunks j and j+8)
        int e0, e1;
        if (isq) {
            e0 = c;           // linear
            e1 = c + 32;
        } else {
            int l7 = l & 7;   // K swizzle: 16B chunk ^= l7, low 8B half kept
            e0 = (((j >> 1) ^ l7) << 3) + ((j & 1) << 2);
            e1 = ((((j >> 1) + 4) ^ l7) << 3) + ((j & 1) << 2);
        }
        u16* orow = dst + ((size_t)(b * H_ + h) * L_ + l) * 64;
        uint2 p0 = {(u32)o[0] | ((u32)o[1] << 16), (u32)o[2] | ((u32)o[3] << 16)};
        uint2 p1 = {(u32)o[4] | ((u32)o[5] << 16), (u32)o[6] | ((u32)o[7] << 16)};
        *(uint2*)(orow + e0) = p0;
        *(uint2*)(orow + e1) = p1;
    } else {
        int bx = blockIdx.x - 4096;
        int bh = bx >> 5, sblk = bx & 31;
        int b = bh >> 3, h = bh & 7;
        int t = threadIdx.x;
        int s0 = sblk * 64;

#pragma unroll
        for (int p = 0; p < 2; ++p) {
            int sl = p * 32 + (t >> 3);
            int c = (t & 7) * 4;
            const float* rp = vin + (((size_t)(b * L_ + s0 + sl)) * H_ + h) * 64;
            float4 a = *(const float4*)(rp + c);
            float4 bb = *(const float4*)(rp + c + 32);
            u32* d0 = (u32*)&tile[sl][c];
            d0[0] = (u32)f2bf(a.x) | ((u32)f2bf(a.y) << 16);
            d0[1] = (u32)f2bf(a.z) | ((u32)f2bf(a.w) << 16);
            u32* d1 = (u32*)&tile[sl][c + 32];
            d1[0] = (u32)f2bf(bb.x) | ((u32)f2bf(bb.y) << 16);
            d1[1] = (u32)f2bf(bb.z) | ((u32)f2bf(bb.w) << 16);
        }
        __syncthreads();
#pragma unroll
        for (int p = 0; p < 2; ++p) {
            int d = p * 32 + (t >> 3);
            int c16 = t & 7;         // logical 16B chunk within the 128B row
            int sc2 = c16 * 8;
            u16 o[8];
#pragma unroll
            for (int i = 0; i < 8; ++i) o[i] = tile[sc2 + i][d];
            u32 w0 = (u32)o[0] | ((u32)o[1] << 16);
            u32 w1 = (u32)o[2] | ((u32)o[3] << 16);
            u32 w2 = (u32)o[4] | ((u32)o[5] << 16);
            u32 w3 = (u32)o[6] | ((u32)o[7] << 16);
            // V swizzle: 8B chunk ^= (d&15). 16B store at chunk c16 ^ (d>>1)&7,
            // with the two 8B halves swapped iff d is odd.
            uint4 val;
            if (d & 1) { val.x = w2; val.y = w3; val.z = w0; val.w = w1; }
            else       { val.x = w0; val.y = w1; val.z = w2; val.w = w3; }
            int pc = c16 ^ ((d >> 1) & 7);
            *(uint4*)(vt + ((size_t)(bh * 32 + sblk) * 64 + d) * 64 + pc * 8) = val;
        }
    }
}

// ---------------------------------------------------------------------------
// Flash attention v19: split-K over-subscription. v13-v18 established the
// bottleneck is occupancy decay (1024 blocks = exactly 4/CU, durations 1..32
// units, no backfill -> makespan = longest block at ~2 waves/SIMD; Occ 23%).
// Now each (bh,qq) task splits into TWO blocks along keys (tiles [0,h0) and
// [h0,qq+1), h0 = ceil((qq+1)/2)) -> 2048 blocks of <=16 units, issued
// longest-first (qq descending, LPT) so retiring blocks are backfilled and
// residency stays ~4-5 blocks/CU for the whole run. Per-block compute is the
// UNCHANGED v17 pipeline (same tile_proc, same registers - avoids v14's
// codegen trap and v12's scheduling trap). Blocks write un-normalized fp32
// O-partials + l-partials (ones-MFMA row-sums) to ws; combine_kernel sums
// halves and normalizes (kernel boundary = bulletproof coherence).
// ---------------------------------------------------------------------------
__global__ __launch_bounds__(256, 4) void flash_kernel(const u16* __restrict__ Qp,
                                                       const u16* __restrict__ Kp,
                                                       const u16* __restrict__ Vt,
                                                       float* __restrict__ pO,
                                                       float* __restrict__ pL) {
    __shared__ u16 kbuf[2][64 * 64];   // 8192 B each, verbatim global tile image
    __shared__ u16 vbuf[2][64 * 64];
    int t = threadIdx.x;
    int wave = t >> 6, lane = t & 63;
    int i = blockIdx.x;
    int half = i & 1;                    // both halves of a task adjacent -> start together
    int tk = i >> 1;                     // task 0..1023
    int bh = tk & 31;                    // fastest -> L2 spread across XCDs
    int qq = 31 - (tk >> 5);             // LPT: longest tasks dispatched first
    int lo = lane & 15, quad = lane >> 4;
    int lo7 = lo & 7;
    int q0 = qq * 64 + wave * 16;

    // this block's tile range [s0, s1)
    int h0 = (qq + 2) >> 1;              // ceil((qq+1)/2)
    int s0 = half ? h0 : 0;
    int s1 = half ? (qq + 1) : h0;

    // lane-constant swizzled element offsets inside a K row (16B chunks)
    int kc0 = (quad ^ lo7) << 3;
    int kc1 = ((quad + 4) ^ lo7) << 3;

    // ones B-operand for the l row-sum MFMA (bf16 1.0 x4)
    u32x2 onespk = {0x3F803F80u, 0x3F803F80u};
    bf16x4 vONES = __builtin_bit_cast(bf16x4, onespk);

    // per-wave static DMA bases: wave owns K-chunks {w, w+4}, V-chunks {w, w+4}
    const u16* kg0 = Kp + (size_t)bh * L_ * 64 + wave * 512 + lane * 8;
    const u16* vg0 = Vt + (size_t)bh * 32 * 64 * 64 + wave * 512 + lane * 8;

    // DMA one 64-key tile pair (K 8KB + V 8KB) into buf: 4 static chunks/wave
    auto stage = [&](int kt, int buf) {
        const u16* kg = kg0 + (size_t)kt * 4096;
        const u16* vg = vg0 + (size_t)kt * 4096;
        u16* kl = kbuf[buf] + wave * 512;
        u16* vl = vbuf[buf] + wave * 512;
        dma16(kg, kl);
        dma16(kg + 2048, kl + 2048);
        dma16(vg, vl);
        dma16(vg + 2048, vl + 2048);
    };

    // Q fragment (B-operand of the S^T MFMA)
    const u16* qbase = Qp + ((size_t)bh * L_ + q0 + lo) * 64 + quad * 8;
    bf16x8 aQ0 = *(const bf16x8*)(qbase);
    bf16x8 aQ1 = *(const bf16x8*)(qbase + 32);
    asm volatile("" :: "v"(aQ0), "v"(aQ1));   // pin early issue, pre-prologue

    f32x4 o[4];
#pragma unroll
    for (int ni = 0; ni < 4; ++ni) o[ni] = (f32x4){0.f, 0.f, 0.f, 0.f};
    f32x4 oL = (f32x4){0.f, 0.f, 0.f, 0.f};   // oL[r] = partial l[q0 + quad*4 + r]

    // full-tile compute, phase-split so all 4 subtile chains overlap (v13/v17)
    auto tile_proc = [&](const u16* ks, const u16* vs) {
        bf16x8 k0[4], k1[4];
#pragma unroll
        for (int sub = 0; sub < 4; ++sub) {
            const u16* krow = ks + ((sub * 16 + lo) << 6);
            k0[sub] = *(const bf16x8*)(krow + kc0);
            k1[sub] = *(const bf16x8*)(krow + kc1);
        }
        bf16x4 vf[4][4];
#pragma unroll
        for (int sub = 0; sub < 4; ++sub) {
            int vsw = ((sub * 4 + quad) ^ lo) << 2;   // swizzled 8B chunk
#pragma unroll
            for (int ni = 0; ni < 4; ++ni)
                vf[sub][ni] = *(const bf16x4*)(vs + ((ni * 16 + lo) << 6) + vsw);
        }
        __builtin_amdgcn_s_setprio(1);
        f32x4 S[4];
#pragma unroll
        for (int sub = 0; sub < 4; ++sub) {
            f32x4 acc = {0.f, 0.f, 0.f, 0.f};
            acc = __builtin_amdgcn_mfma_f32_16x16x32_bf16(k0[sub], aQ0, acc, 0, 0, 0);
            S[sub] = __builtin_amdgcn_mfma_f32_16x16x32_bf16(k1[sub], aQ1, acc, 0, 0, 0);
        }
        bf16x4 aP[4];
#pragma unroll
        for (int sub = 0; sub < 4; ++sub) {
            float P0 = __builtin_amdgcn_exp2f(S[sub][0]);
            float P1 = __builtin_amdgcn_exp2f(S[sub][1]);
            float P2 = __builtin_amdgcn_exp2f(S[sub][2]);
            float P3 = __builtin_amdgcn_exp2f(S[sub][3]);
            u32x2 pk = {pk2bf(P0, P1), pk2bf(P2, P3)};
            aP[sub] = __builtin_bit_cast(bf16x4, pk);
        }
#pragma unroll
        for (int sub = 0; sub < 4; ++sub) {
#pragma unroll
            for (int ni = 0; ni < 4; ++ni)
                o[ni] = mfma16x16x16bf16(aP[sub], vf[sub][ni], o[ni]);
            oL = mfma16x16x16bf16(aP[sub], vONES, oL);
        }
        __builtin_amdgcn_s_setprio(0);
    };

    // serial per-sub path, used only for the diagonal tile
    auto frag_proc = [&](const u16* ks, const u16* vs, int sub, bool diag) {
        const u16* krow = ks + ((sub * 16 + lo) << 6);
        bf16x8 k0 = *(const bf16x8*)(krow + kc0);
        bf16x8 k1 = *(const bf16x8*)(krow + kc1);
        f32x4 S = {0.f, 0.f, 0.f, 0.f};
        S = __builtin_amdgcn_mfma_f32_16x16x32_bf16(k0, aQ0, S, 0, 0, 0);
        S = __builtin_amdgcn_mfma_f32_16x16x32_bf16(k1, aQ1, S, 0, 0, 0);

        int vsw = ((sub * 4 + quad) ^ lo) << 2;   // swizzled 8B chunk offset
        bf16x4 vf[4];
#pragma unroll
        for (int ni = 0; ni < 4; ++ni)
            vf[ni] = *(const bf16x4*)(vs + ((ni * 16 + lo) << 6) + vsw);

        float P[4];
#pragma unroll
        for (int r = 0; r < 4; ++r) {
            float e = __builtin_amdgcn_exp2f(S[r]);
            P[r] = (diag && (quad * 4 + r > lo)) ? 0.f : e;
        }
        u32x2 pk = {pk2bf(P[0], P[1]), pk2bf(P[2], P[3])};
        bf16x4 aP = __builtin_bit_cast(bf16x4, pk);
#pragma unroll
        for (int ni = 0; ni < 4; ++ni)
            o[ni] = mfma16x16x16bf16(aP, vf[ni], o[ni]);
        oL = mfma16x16x16bf16(aP, vONES, oL);
    };

    if (s1 > s0) {
        // ---- prologue: DMA tile s0 -> buf0 ----
        stage(s0, 0);
        __syncthreads();
        int cur = 0;
        // ---- full tiles s0..s1-2: DMA kt+1 first, compute kt, sync ----
        for (int kt = s0; kt < s1 - 1; ++kt) {
            stage(kt + 1, cur ^ 1);
            tile_proc(kbuf[cur], vbuf[cur]);
            __syncthreads();
            cur ^= 1;
        }
        // ---- last tile: diagonal iff this block owns tile qq ----
        if (s1 - 1 == qq) {
            const u16* ks = kbuf[cur];
            const u16* vs = vbuf[cur];
            __builtin_amdgcn_s_setprio(1);
            for (int sub = 0; sub < wave; ++sub) frag_proc(ks, vs, sub, false);
            frag_proc(ks, vs, wave, true);
            __builtin_amdgcn_s_setprio(0);
        } else {
            tile_proc(kbuf[cur], vbuf[cur]);
        }
    }
    // (nt==0 blocks fall through with o/oL == 0 -> write zero partials)

    // ---- epilogue: write un-normalized partials for this (task, half) ----
    int slot = ((qq * 32 + bh) << 1) + half;
    float* pout = pO + (size_t)slot * 4096;          // 64 rows x 64 cols
    float* plp = pL + slot * 64;
#pragma unroll
    for (int r = 0; r < 4; ++r) {
        int rr = wave * 16 + quad * 4 + r;
        float* ob = pout + rr * 64 + lo;
        ob[0]  = o[0][r];
        ob[16] = o[1][r];
        ob[32] = o[2][r];
        ob[48] = o[3][r];
        if (lo == 0) plp[rr] = oL[r];
    }
}

// ---------------------------------------------------------------------------
// Combine: out = (pO[half0] + pO[half1]) / (pL[half0] + pL[half1]).
// 1024 blocks (one per task) x 256 threads; thread -> row t>>2, col (t&3)*16.
// Fully coalesced 16B loads/stores; partials are L2/L3-resident.
// ---------------------------------------------------------------------------
__global__ __launch_bounds__(256) void combine_kernel(const float* __restrict__ pO,
                                                      const float* __restrict__ pL,
                                                      float* __restrict__ out) {
    int c = blockIdx.x;                  // qq = c>>5, bh = c&31
    int qq = c >> 5, bh = c & 31;
    int b = bh >> 3, h = bh & 7;
    int t = threadIdx.x;
    int rr = t >> 2;
    int cq = (t & 3) * 16;
    int slot0 = ((qq * 32 + bh) << 1);
    const float* pa = pO + (size_t)slot0 * 4096 + rr * 64 + cq;
    const float* pb = pa + 4096;
    float l = pL[slot0 * 64 + rr] + pL[(slot0 + 1) * 64 + rr];
    float inv = 1.0f / l;
    int q = qq * 64 + rr;
    float* ob = out + (((size_t)(b * L_ + q)) * H_ + h) * 64 + cq;
#pragma unroll
    for (int j = 0; j < 4; ++j) {
        f32x4 va = *(const f32x4*)(pa + j * 4);
        f32x4 vb = *(const f32x4*)(pb + j * 4);
        f32x4 vr = (va + vb) * inv;
        *(f32x4*)(ob + j * 4) = vr;
    }
}

extern "C" void kernel_launch(void* const* d_in, const int* in_sizes, int n_in,
                              void* d_out, int out_size, void* d_ws, size_t ws_size,
                              hipStream_t stream) {
    const float* q = (const float*)d_in[0];
    const float* k = (const float*)d_in[1];
    const float* v = (const float*)d_in[2];
    // d_in[3] = attn_mask: deterministic causal, recomputed analytically.
    float* out = (float*)d_out;

    const size_t QSZ = (size_t)B_ * H_ * L_ * 64;     // elements (u16)
    u16* qp = (u16*)d_ws;
    u16* kp = qp + QSZ;
    u16* vt = kp + QSZ;
    // fp32 partials after the three u16 arrays (3*QSZ u16 = 24MB, 16B-aligned)
    float* pO = (float*)(vt + QSZ);                   // 1024*2*64*64 = 33.6MB
    float* pL = pO + (size_t)2048 * 4096;             // 1024*2*64    = 0.5MB

    prep_kernel<<<5120, 256, 0, stream>>>(q, k, v, qp, kp, vt);
    flash_kernel<<<2048, 256, 0, stream>>>(qp, kp, vt, pO, pL);
    combine_kernel<<<1024, 256, 0, stream>>>(pO, pL, out);
}

// Round 10
// 156.941 us; speedup vs baseline: 1.0654x; 1.0654x over previous
//
#include <hip/hip_runtime.h>
#include <hip/hip_bf16.h>
#include <stdint.h>

#define B_ 4
#define L_ 2048
#define H_ 8
#define E_ 64
#define ALPHA 0.1f
#define LOG2E 1.44269504088896f
// Q prescale: 1/sqrt(64) * log2(e) folded into projected Q so P = exp2(S)
#define QSCALE (0.125f * LOG2E)

// Tiles are contiguous 64*128B = 8192B, DMA'd verbatim to LDS.
// K tile image: row r (0..63), 16B chunk c (0..7) stored at chunk c ^ (r&7).
// V tile image: row d (0..63), 8B  chunk c (0..15) stored at chunk c ^ (d&15).
// XOR swizzle is applied identically on the prep write side (global) and the
// flash read side (LDS) -> DMA stays linear, reads are bank-conflict-free.

typedef float f32x4 __attribute__((ext_vector_type(4)));
typedef short bf16x8 __attribute__((ext_vector_type(8)));
typedef short bf16x4 __attribute__((ext_vector_type(4)));
typedef uint32_t u32;
typedef unsigned short u16;
typedef u32 u32x2 __attribute__((ext_vector_type(2)));

__device__ __forceinline__ u16 f2bf(float f) {
    u32 x = __builtin_bit_cast(u32, f);
    u32 r = x + 0x7fffu + ((x >> 16) & 1u);   // round-to-nearest-even
    return (u16)(r >> 16);
}

// pack two positive floats to packed bf16 (round-half-up; P>0, never NaN).
// NOTE (r6 post-mortem): v_cvt_pk_bf16_f32 inline asm here FAILED correctness
// (absmax 0.47). Keep the verified bit-op version.
__device__ __forceinline__ u32 pk2bf(float a, float b) {
    u32 ua = __builtin_bit_cast(u32, a) + 0x8000u;
    u32 ub = __builtin_bit_cast(u32, b) + 0x8000u;
    return (ua >> 16) | (ub & 0xffff0000u);
}

__device__ __forceinline__ f32x4 mfma16x16x16bf16(bf16x4 a, bf16x4 b, f32x4 c) {
#if __has_builtin(__builtin_amdgcn_mfma_f32_16x16x16bf16_1k)
    return __builtin_amdgcn_mfma_f32_16x16x16bf16_1k(a, b, c, 0, 0, 0);
#elif __has_builtin(__builtin_amdgcn_mfma_f32_16x16x16_bf16)
    return __builtin_amdgcn_mfma_f32_16x16x16_bf16(a, b, c, 0, 0, 0);
#else
    f32x4 d;
    asm volatile("v_mfma_f32_16x16x16_bf16 %0, %1, %2, %3"
                 : "=v"(d) : "v"(a), "v"(b), "v"(c));
    return d;
#endif
}

// async DMA: 64 lanes x 16B, dest = wave-uniform LDS base + lane*16
__device__ __forceinline__ void dma16(const u16* g, u16* l) {
    __builtin_amdgcn_global_load_lds(
        (const __attribute__((address_space(1))) void*)g,
        (__attribute__((address_space(3))) void*)l, 16, 0, 0);
}

// ---------------------------------------------------------------------------
// Prep kernel (fused): unchanged (passing, ~4.5us, L3-fed).
// ---------------------------------------------------------------------------
__global__ __launch_bounds__(256) void prep_kernel(const float* __restrict__ qin,
                                                   const float* __restrict__ kin,
                                                   const float* __restrict__ vin,
                                                   u16* __restrict__ qp,
                                                   u16* __restrict__ kp,
                                                   u16* __restrict__ vt) {
    __shared__ u16 tile[64][66];
    if (blockIdx.x < 4096) {
        const int RG = (B_ * L_ * H_) / 8;
        int wave = threadIdx.x >> 6, lane = threadIdx.x & 63;
        int g = blockIdx.x * 4 + wave;
        const float* src;
        u16* dst;
        int gr;
        float sc;
        bool isq;
        if (g < RG) { src = qin; dst = qp; gr = g; sc = QSCALE; isq = true; }
        else        { src = kin; dst = kp; gr = g - RG; sc = 1.0f; isq = false; }

        int rig = lane >> 3;
        int j = lane & 7;
        int c = j * 4;
        int row = gr * 8 + rig;

        const float* rp = src + (size_t)row * 64;
        float4 v0 = *(const float4*)(rp + c);
        float4 v1 = *(const float4*)(rp + c + 32);
        float f[8] = {v0.x, v0.y, v0.z, v0.w, v1.x, v1.y, v1.z, v1.w};

        float mx = 0.f;
#pragma unroll
        for (int i = 0; i < 8; ++i) mx = fmaxf(mx, fabsf(f[i]));
#pragma unroll
        for (int m = 1; m < 8; m <<= 1) mx = fmaxf(mx, __shfl_xor(mx, m));
        float thr = ALPHA * mx;

        u16 o[8];
#pragma unroll
        for (int i = 0; i < 8; ++i)
            o[i] = (fabsf(f[i]) >= thr) ? f2bf(f[i] * sc) : (u16)0;

        int b = row >> 14;
        int l = (row >> 3) & (L_ - 1);
        int h = row & 7;
        // element offsets for the two 8B writes (logical chunks j and j+8)
        int e0, e1;
        if (isq) {
            e0 = c;           // linear
            e1 = c + 32;
        } else {
            int l7 = l & 7;   // K swizzle: 16B chunk ^= l7, low 8B half kept
            e0 = (((j >> 1) ^ l7) << 3) + ((j & 1) << 2);
            e1 = ((((j >> 1) + 4) ^ l7) << 3) + ((j & 1) << 2);
        }
        u16* orow = dst + ((size_t)(b * H_ + h) * L_ + l) * 64;
        uint2 p0 = {(u32)o[0] | ((u32)o[1] << 16), (u32)o[2] | ((u32)o[3] << 16)};
        uint2 p1 = {(u32)o[4] | ((u32)o[5] << 16), (u32)o[6] | ((u32)o[7] << 16)};
        *(uint2*)(orow + e0) = p0;
        *(uint2*)(orow + e1) = p1;
    } else {
        int bx = blockIdx.x - 4096;
        int bh = bx >> 5, sblk = bx & 31;
        int b = bh >> 3, h = bh & 7;
        int t = threadIdx.x;
        int s0 = sblk * 64;

#pragma unroll
        for (int p = 0; p < 2; ++p) {
            int sl = p * 32 + (t >> 3);
            int c = (t & 7) * 4;
            const float* rp = vin + (((size_t)(b * L_ + s0 + sl)) * H_ + h) * 64;
            float4 a = *(const float4*)(rp + c);
            float4 bb = *(const float4*)(rp + c + 32);
            u32* d0 = (u32*)&tile[sl][c];
            d0[0] = (u32)f2bf(a.x) | ((u32)f2bf(a.y) << 16);
            d0[1] = (u32)f2bf(a.z) | ((u32)f2bf(a.w) << 16);
            u32* d1 = (u32*)&tile[sl][c + 32];
            d1[0] = (u32)f2bf(bb.x) | ((u32)f2bf(bb.y) << 16);
            d1[1] = (u32)f2bf(bb.z) | ((u32)f2bf(bb.w) << 16);
        }
        __syncthreads();
#pragma unroll
        for (int p = 0; p < 2; ++p) {
            int d = p * 32 + (t >> 3);
            int c16 = t & 7;         // logical 16B chunk within the 128B row
            int sc2 = c16 * 8;
            u16 o[8];
#pragma unroll
            for (int i = 0; i < 8; ++i) o[i] = tile[sc2 + i][d];
            u32 w0 = (u32)o[0] | ((u32)o[1] << 16);
            u32 w1 = (u32)o[2] | ((u32)o[3] << 16);
            u32 w2 = (u32)o[4] | ((u32)o[5] << 16);
            u32 w3 = (u32)o[6] | ((u32)o[7] << 16);
            // V swizzle: 8B chunk ^= (d&15). 16B store at chunk c16 ^ (d>>1)&7,
            // with the two 8B halves swapped iff d is odd.
            uint4 val;
            if (d & 1) { val.x = w2; val.y = w3; val.z = w0; val.w = w1; }
            else       { val.x = w0; val.y = w1; val.z = w2; val.w = w3; }
            int pc = c16 ^ ((d >> 1) & 7);
            *(uint4*)(vt + ((size_t)(bh * 32 + sblk) * 64 + d) * 64 + pc * 8) = val;
        }
    }
}

// ---------------------------------------------------------------------------
// Flash attention v20 = v13 compute (the 160.7us best: phase-split ILP,
// shuffle epilogue, no setprio/ones-MFMA) + counted-vmcnt sync (T3/T4 recipe):
//   prologue: stage tile0 AND tile1 (8 DMAs in flight / wave)
//   per iter: s_waitcnt vmcnt(4)   <- waits ONLY the oldest 4 = tile kt;
//             s_barrier            <- every wave confirmed its own 4 -> all
//                                     16 chunks of tile kt landed
//             compute(buf[kt&1])
//             s_barrier            <- all waves done reading buf[kt&1]
//             stage(kt+2, kt&1)    <- overwrite is safe; 2-tile slack
// No vmcnt(0) in the main loop (v13's __syncthreads drained the just-issued
// DMA every iteration = the m97-style ~20% stall; v19 proved the stall is
// per-block-independent: backfill gave zero gain). v12's regression was 3
// "memory"-fenced asm blocks/iter + useless K-depth; this is 1 fence/iter.
// Static 4-DMA stage for a deterministic per-wave vmcnt count.
// Grid: 1024 = 32 qq-groups x 32 bh; qq interleaved so each CU sums 66 units.
// ---------------------------------------------------------------------------
__global__ __launch_bounds__(256, 4) void flash_kernel(const u16* __restrict__ Qp,
                                                       const u16* __restrict__ Kp,
                                                       const u16* __restrict__ Vt,
                                                       float* __restrict__ out) {
    __shared__ u16 kbuf[2][64 * 64];   // 8192 B each, verbatim global tile image
    __shared__ u16 vbuf[2][64 * 64];
    int t = threadIdx.x;
    int wave = t >> 6, lane = t & 63;
    int bh = blockIdx.x & 31;            // fastest -> bh mod 8 pins XCD (L2 locality)
    int r5 = blockIdx.x >> 5;            // 0..31
    int g = r5 & 7, kr = r5 >> 3;
    // per-CU-balanced interleave: sums of (qq+1) over the 4 rounds = 66 for all g
    int qq = (kr == 0) ? (31 - g) : (kr == 1) ? (16 + g) : (kr == 2) ? (15 - g) : g;
    int lo = lane & 15, quad = lane >> 4;
    int lo7 = lo & 7;
    int q0 = qq * 64 + wave * 16;
    int b = bh >> 3, h = bh & 7;

    // lane-constant swizzled element offsets inside a K row (16B chunks)
    int kc0 = (quad ^ lo7) << 3;
    int kc1 = ((quad + 4) ^ lo7) << 3;

    // per-wave static DMA bases: wave owns K-chunks {w, w+4}, V-chunks {w, w+4}
    const u16* kg0 = Kp + (size_t)bh * L_ * 64 + wave * 512 + lane * 8;
    const u16* vg0 = Vt + (size_t)bh * 32 * 64 * 64 + wave * 512 + lane * 8;

    // DMA one 64-key tile pair (K 8KB + V 8KB) into buf: exactly 4 DMAs/wave
    auto stage = [&](int kt, int buf) {
        const u16* kg = kg0 + (size_t)kt * 4096;
        const u16* vg = vg0 + (size_t)kt * 4096;
        u16* kl = kbuf[buf] + wave * 512;
        u16* vl = vbuf[buf] + wave * 512;
        dma16(kg, kl);
        dma16(kg + 2048, kl + 2048);
        dma16(vg, vl);
        dma16(vg + 2048, vl + 2048);
    };

    // Q fragment (B-operand of the S^T MFMA)
    const u16* qbase = Qp + ((size_t)bh * L_ + q0 + lo) * 64 + quad * 8;
    bf16x8 aQ0 = *(const bf16x8*)(qbase);
    bf16x8 aQ1 = *(const bf16x8*)(qbase + 32);
    asm volatile("" :: "v"(aQ0), "v"(aQ1));   // pin early issue, pre-prologue

    f32x4 o[4];
#pragma unroll
    for (int ni = 0; ni < 4; ++ni) o[ni] = (f32x4){0.f, 0.f, 0.f, 0.f};
    float ls = 0.f;   // per-lane partial of l[q=q0+lo] (this quad's s-slices)

    // full-tile compute, phase-split so all 4 subtile chains overlap (v13)
    auto tile_proc = [&](const u16* ks, const u16* vs) {
        // phase 1: all K fragment loads (8 x ds_read_b128)
        bf16x8 k0[4], k1[4];
#pragma unroll
        for (int sub = 0; sub < 4; ++sub) {
            const u16* krow = ks + ((sub * 16 + lo) << 6);
            k0[sub] = *(const bf16x8*)(krow + kc0);
            k1[sub] = *(const bf16x8*)(krow + kc1);
        }
        // phase 2: all V fragment loads (16 x ds_read_b64)
        bf16x4 vf[4][4];
#pragma unroll
        for (int sub = 0; sub < 4; ++sub) {
            int vsw = ((sub * 4 + quad) ^ lo) << 2;   // swizzled 8B chunk
#pragma unroll
            for (int ni = 0; ni < 4; ++ni)
                vf[sub][ni] = *(const bf16x4*)(vs + ((ni * 16 + lo) << 6) + vsw);
        }
        // phase 3: all S MFMAs (4 independent 2-chains)
        f32x4 S[4];
#pragma unroll
        for (int sub = 0; sub < 4; ++sub) {
            f32x4 acc = {0.f, 0.f, 0.f, 0.f};
            acc = __builtin_amdgcn_mfma_f32_16x16x32_bf16(k0[sub], aQ0, acc, 0, 0, 0);
            S[sub] = __builtin_amdgcn_mfma_f32_16x16x32_bf16(k1[sub], aQ1, acc, 0, 0, 0);
        }
        // phase 4: softmax VALU for all subs
        bf16x4 aP[4];
#pragma unroll
        for (int sub = 0; sub < 4; ++sub) {
            float P0 = __builtin_amdgcn_exp2f(S[sub][0]);
            float P1 = __builtin_amdgcn_exp2f(S[sub][1]);
            float P2 = __builtin_amdgcn_exp2f(S[sub][2]);
            float P3 = __builtin_amdgcn_exp2f(S[sub][3]);
            ls += (P0 + P1) + (P2 + P3);
            u32x2 pk = {pk2bf(P0, P1), pk2bf(P2, P3)};
            aP[sub] = __builtin_bit_cast(bf16x4, pk);
        }
        // phase 5: all 16 PV MFMAs (4 independent o[ni] chains)
#pragma unroll
        for (int sub = 0; sub < 4; ++sub)
#pragma unroll
            for (int ni = 0; ni < 4; ++ni)
                o[ni] = mfma16x16x16bf16(aP[sub], vf[sub][ni], o[ni]);
    };

    // serial per-sub path, used only for the diagonal tile
    auto frag_proc = [&](const u16* ks, const u16* vs, int sub, bool diag) {
        const u16* krow = ks + ((sub * 16 + lo) << 6);
        bf16x8 k0 = *(const bf16x8*)(krow + kc0);
        bf16x8 k1 = *(const bf16x8*)(krow + kc1);
        f32x4 S = {0.f, 0.f, 0.f, 0.f};
        S = __builtin_amdgcn_mfma_f32_16x16x32_bf16(k0, aQ0, S, 0, 0, 0);
        S = __builtin_amdgcn_mfma_f32_16x16x32_bf16(k1, aQ1, S, 0, 0, 0);

        int vsw = ((sub * 4 + quad) ^ lo) << 2;   // swizzled 8B chunk offset
        bf16x4 vf[4];
#pragma unroll
        for (int ni = 0; ni < 4; ++ni)
            vf[ni] = *(const bf16x4*)(vs + ((ni * 16 + lo) << 6) + vsw);

        float P[4];
#pragma unroll
        for (int r = 0; r < 4; ++r) {
            float e = __builtin_amdgcn_exp2f(S[r]);
            P[r] = (diag && (quad * 4 + r > lo)) ? 0.f : e;
        }
        ls += (P[0] + P[1]) + (P[2] + P[3]);
        u32x2 pk = {pk2bf(P[0], P[1]), pk2bf(P[2], P[3])};
        bf16x4 aP = __builtin_bit_cast(bf16x4, pk);
#pragma unroll
        for (int ni = 0; ni < 4; ++ni)
            o[ni] = mfma16x16x16bf16(aP, vf[ni], o[ni]);
    };

    // ---- prologue: 2 tiles in flight (8 DMAs/wave) ----
    stage(0, 0);
    if (qq >= 1) stage(1, 1);

    // ---- full tiles 0..qq-1: counted vmcnt, no full drain in the loop ----
    for (int kt = 0; kt < qq; ++kt) {
        // oldest 4 of this wave's DMAs = tile kt; tile kt+1's 4 stay in flight
        asm volatile("s_waitcnt vmcnt(4)" ::: "memory");
        __builtin_amdgcn_s_barrier();      // now ALL waves' tile-kt chunks landed
        tile_proc(kbuf[kt & 1], vbuf[kt & 1]);
        __builtin_amdgcn_s_barrier();      // all waves done reading buf[kt&1]
        if (kt + 2 <= qq) stage(kt + 2, kt & 1);
    }

    // ---- diagonal tile qq (in buf[qq&1]): drain the last in-flight DMAs ----
    {
        asm volatile("s_waitcnt vmcnt(0)" ::: "memory");
        __builtin_amdgcn_s_barrier();
        const u16* ks = kbuf[qq & 1];
        const u16* vs = vbuf[qq & 1];
        for (int sub = 0; sub < wave; ++sub) frag_proc(ks, vs, sub, false);
        frag_proc(ks, vs, wave, true);
    }

    // ---- epilogue: full l on every lane, normalize, store fp32 ----
    ls += __shfl_xor(ls, 16);
    ls += __shfl_xor(ls, 32);
#pragma unroll
    for (int r = 0; r < 4; ++r) {
        float lr = __shfl(ls, quad * 4 + r);   // l for output row q0+quad*4+r
        float inv = 1.0f / lr;
        int q = q0 + quad * 4 + r;
        float* ob = out + (((size_t)(b * L_ + q)) * H_ + h) * 64 + lo;
        ob[0]  = o[0][r] * inv;
        ob[16] = o[1][r] * inv;
        ob[32] = o[2][r] * inv;
        ob[48] = o[3][r] * inv;
    }
}

extern "C" void kernel_launch(void* const* d_in, const int* in_sizes, int n_in,
                              void* d_out, int out_size, void* d_ws, size_t ws_size,
                              hipStream_t stream) {
    const float* q = (const float*)d_in[0];
    const float* k = (const float*)d_in[1];
    const float* v = (const float*)d_in[2];
    // d_in[3] = attn_mask: deterministic causal, recomputed analytically.
    float* out = (float*)d_out;

    const size_t QSZ = (size_t)B_ * H_ * L_ * 64;     // elements
    u16* qp = (u16*)d_ws;
    u16* kp = qp + QSZ;
    u16* vt = kp + QSZ;

    prep_kernel<<<5120, 256, 0, stream>>>(q, k, v, qp, kp, vt);
    flash_kernel<<<1024, 256, 0, stream>>>(qp, kp, vt, out);
}